// Round 1
// baseline (214.774 us; speedup 1.0000x reference)
//
#include <hip/hip_runtime.h>
#include <cmath>

// Problem constants (from reference setup_inputs)
#define B_  32
#define S_  52
#define A_  5
#define C_  80
#define T_  50
#define PD_ (A_ * (5 + C_))   // 425 channels per spatial cell

__constant__ float c_anchors[A_ * 2] = {
    1.3221f, 1.73145f,
    3.19275f, 4.00944f,
    5.05587f, 8.09892f,
    9.47112f, 4.84053f,
    11.2364f, 10.0071f
};

__device__ __forceinline__ float sigmoidf_(float x) {
    return 1.0f / (1.0f + __expf(-x));
}

// ws layout (floats): [0]=sum_conf2_all  [1]=S_off  [2]=S_scale  [3]=S_obj  [4]=S_conf2_winners

// Kernel 1: sum of sigmoid(obj_score)^2 over all B*S*S*A cells.
// obj_score lives at channel a*85+4 within each 425-float cell row.
__global__ __launch_bounds__(256) void conf2_sum_kernel(
        const float* __restrict__ pred, float* __restrict__ acc) {
    const int total = B_ * S_ * S_ * A_;   // 432640 == 1690*256 exactly
    int idx = blockIdx.x * blockDim.x + threadIdx.x;
    float v = 0.0f;
    if (idx < total) {
        int a = idx % A_;
        int cell = idx / A_;               // b*S*S + i*S + j
        float conf = sigmoidf_(pred[(size_t)cell * PD_ + a * 85 + 4]);
        v = conf * conf;
    }
    // wave64 reduce
    #pragma unroll
    for (int off = 32; off > 0; off >>= 1)
        v += __shfl_down(v, off, 64);
    __shared__ float lds[4];
    int lane = threadIdx.x & 63;
    int wv = threadIdx.x >> 6;
    if (lane == 0) lds[wv] = v;
    __syncthreads();
    if (threadIdx.x == 0) {
        atomicAdd(acc, lds[0] + lds[1] + lds[2] + lds[3]);
    }
}

// Kernel 2: per-target terms. One wave per batch image; lane t handles target t.
// Dedupe scattered cells with last-target-wins (matches sequential scatter order).
__global__ __launch_bounds__(64) void target_kernel(
        const float* __restrict__ pred, const float* __restrict__ tgt,
        float* __restrict__ acc) {
    const int b = blockIdx.x;
    const int t = threadIdx.x;
    __shared__ int cellids[T_];

    float gx = 0.f, gy = 0.f, gw = 0.f, gh = 0.f;
    float baw = 1.f, bah = 1.f;
    int best_a = 0, gi = 0, gj = 0;
    const bool active = (t < T_);

    if (active) {
        const float* tp = tgt + ((size_t)b * T_ + t) * 5;
        gx = tp[0]; gy = tp[1]; gw = tp[2]; gh = tp[3];
        float gtw = gw * S_, gth = gh * S_;
        float best = -1.0f;
        #pragma unroll
        for (int a = 0; a < A_; ++a) {
            float aw = c_anchors[2 * a], ah = c_anchors[2 * a + 1];
            float inter = fminf(gtw, aw) * fminf(gth, ah);
            float uni = gtw * gth + aw * ah - inter;
            float iou = (uni > 0.0f) ? (inter / uni) : 0.0f;
            if (iou > best) { best = iou; best_a = a; baw = aw; bah = ah; }  // first-max wins (strict >)
        }
        gi = (int)(gx * S_);   // truncation == floor for positives
        gj = (int)(gy * S_);
        cellids[t] = (best_a * S_ + gj) * S_ + gi;
    }
    __syncthreads();

    bool winner = active;
    if (active) {
        int myid = cellids[t];
        for (int u = t + 1; u < T_; ++u)
            if (cellids[u] == myid) { winner = false; break; }
    }

    float s_off = 0.f, s_scale = 0.f, s_obj = 0.f, s_conf2 = 0.f;
    if (winner) {
        float gtw = gw * S_, gth = gh * S_;
        const float* p = pred + (((size_t)b * S_ + gj) * S_ + gi) * PD_ + best_a * 85;
        float tx = p[0], ty = p[1], tw = p[2], th = p[3], to = p[4];

        float pbx = sigmoidf_(tx), pby = sigmoidf_(ty);
        float pbw = __expf(tw) * baw, pbh = __expf(th) * bah;
        float ggx = gx * S_ - (float)gi, ggy = gy * S_ - (float)gj;

        // IoU between ground (cx=ggx+gi, cy=ggy+gj, gtw, gth) and pred box
        float cx1 = ggx + (float)gi, cy1 = ggy + (float)gj;
        float cx2 = pbx + (float)gi, cy2 = pby + (float)gj;
        float ix = fmaxf(0.0f, fminf(cx1 + gtw * 0.5f, cx2 + pbw * 0.5f)
                             - fmaxf(cx1 - gtw * 0.5f, cx2 - pbw * 0.5f));
        float iy = fmaxf(0.0f, fminf(cy1 + gth * 0.5f, cy2 + pbh * 0.5f)
                             - fmaxf(cy1 - gth * 0.5f, cy2 - pbh * 0.5f));
        float inter = ix * iy;
        float uni = gtw * gth + pbw * pbh - inter;
        float iou = (uni > 0.0f) ? (inter / uni) : 0.0f;

        float conf = sigmoidf_(to);

        s_off = (pbx - ggx) * (pbx - ggx) + (pby - ggy) * (pby - ggy);
        const float eps = 1e-6f;
        float dw = sqrtf(pbw + eps) - sqrtf(gtw + eps);
        float dh = sqrtf(pbh + eps) - sqrtf(gth + eps);
        s_scale = dw * dw + dh * dh;
        s_obj = (iou - conf) * (iou - conf);
        s_conf2 = conf * conf;   // to remove from the all-cells no-obj sum
    }

    #pragma unroll
    for (int off = 32; off > 0; off >>= 1) {
        s_off   += __shfl_down(s_off,   off, 64);
        s_scale += __shfl_down(s_scale, off, 64);
        s_obj   += __shfl_down(s_obj,   off, 64);
        s_conf2 += __shfl_down(s_conf2, off, 64);
    }
    if (t == 0) {
        atomicAdd(acc + 1, s_off);
        atomicAdd(acc + 2, s_scale);
        atomicAdd(acc + 3, s_obj);
        atomicAdd(acc + 4, s_conf2);
    }
}

// Kernel 3: compose the three outputs (note lambdas applied twice, per reference).
__global__ void finalize_kernel(const float* __restrict__ acc, float* __restrict__ out) {
    float sum_all = acc[0];
    float s_off = acc[1], s_scale = acc[2], s_obj = acc[3], s_c2w = acc[4];
    float loss_coord = 5.0f * (s_off + s_scale);         // offset+scale, each already *5
    float loss_no_obj = 0.5f * (sum_all - s_c2w);
    float loss_obj = s_obj;
    out[0] = 5.0f * loss_coord + loss_obj + 0.5f * loss_no_obj;
    out[1] = loss_coord;
    out[2] = loss_obj + loss_no_obj;
}

extern "C" void kernel_launch(void* const* d_in, const int* in_sizes, int n_in,
                              void* d_out, int out_size, void* d_ws, size_t ws_size,
                              hipStream_t stream) {
    const float* pred = (const float*)d_in[0];   // [32,52,52,425]
    const float* tgt  = (const float*)d_in[1];   // [32,50,5]
    float* out = (float*)d_out;                  // 3 scalars
    float* acc = (float*)d_ws;                   // 5 accumulators

    hipMemsetAsync(acc, 0, 5 * sizeof(float), stream);

    const int total = B_ * S_ * S_ * A_;         // 432640
    conf2_sum_kernel<<<(total + 255) / 256, 256, 0, stream>>>(pred, acc);
    target_kernel<<<B_, 64, 0, stream>>>(pred, tgt, acc);
    finalize_kernel<<<1, 1, 0, stream>>>(acc, out);
}